// Round 19
// baseline (64.944 us; speedup 1.0000x reference)
//
#include <hip/hip_runtime.h>
#include <hip/hip_bf16.h>

typedef short bf16x8 __attribute__((ext_vector_type(8)));
typedef float f32x4 __attribute__((ext_vector_type(4)));

constexpr int B_ = 16;
constexpr int L_ = 2048;
constexpr int DM = 512;
constexpr int NS = 64;
constexpr int BL = B_ * L_;          // 32768 rows
constexpr float LN_EPS = 1e-5f;
constexpr float KLN = 2.8853900817779268f;   // 2*log2(e)

constexpr int SEGS = 32;
constexpr int LSEG = L_ / SEGS;      // 64 live rows per scan
constexpr int WARM = 64;

__device__ __forceinline__ unsigned f32bits(float f) {
    union { float f; unsigned u; } v{f}; return v.u;
}
__device__ __forceinline__ float bitsf32(unsigned u) {
    union { unsigned u; float f; } v{u}; return v.f;
}
__device__ __forceinline__ unsigned short f2bf(float f) {   // RNE
    unsigned u = f32bits(f);
    unsigned r = u + 0x7FFF + ((u >> 16) & 1);
    return (unsigned short)(r >> 16);
}

// normalize 8 consecutive-k x values and split into hi/lo bf16 fragments.
__device__ __forceinline__ void norm_split8(float4 u0, float4 u1,
                                            float rstd, float m2,
                                            bf16x8& ah, bf16x8& al) {
    float t[8] = { fmaf(u0.x, rstd, m2), fmaf(u0.y, rstd, m2),
                   fmaf(u0.z, rstd, m2), fmaf(u0.w, rstd, m2),
                   fmaf(u1.x, rstd, m2), fmaf(u1.y, rstd, m2),
                   fmaf(u1.z, rstd, m2), fmaf(u1.w, rstd, m2) };
    unsigned hb[8], lb[8];
    #pragma unroll
    for (int j = 0; j < 8; ++j) {
        unsigned tb = f32bits(t[j]);
        hb[j] = tb & 0xFFFF0000u;
        lb[j] = f32bits(t[j] - bitsf32(hb[j]));
    }
    union { unsigned u[4]; bf16x8 v; } H, L;
    #pragma unroll
    for (int p = 0; p < 4; ++p) {
        H.u[p] = (hb[2*p] >> 16) | hb[2*p+1];
        L.u[p] = (lb[2*p] >> 16) | (lb[2*p+1] & 0xFFFF0000u);
    }
    ah = H.v; al = L.v;
}

// ---- Kernel 0: pack A' = diag(gamma)@A split MFMA-B fragments; C into the
//      swapped-operand interleaved fragment order PC2 (validated R9/R12);
//      c0 = beta@A; gd = gamma*D; bd = beta*D ----
__global__ __launch_bounds__(256) void k_pack(const float* __restrict__ A,
                                              const float* __restrict__ C,
                                              const float* __restrict__ gamma,
                                              const float* __restrict__ beta,
                                              const float* __restrict__ Dv,
                                              unsigned short* __restrict__ PAh,
                                              unsigned short* __restrict__ PAl,
                                              unsigned short* __restrict__ PC2,
                                              float* __restrict__ c0,
                                              float* __restrict__ gd,
                                              float* __restrict__ bd) {
    const int blk = blockIdx.x;
    const int tid = threadIdx.x;
    if (blk < 32) {
        const int g = blk * 256 + tid;     // 0..8191
        if (g < 4096) {
            const int lane = g & 63, ct = (g >> 6) & 3, k32 = (g >> 8) & 3, kc = g >> 10;
            const int kbase = kc * 128 + k32 * 32 + (lane >> 4) * 8;
            const int col   = ct * 16 + (lane & 15);
            unsigned hb[8], lb[8];
            #pragma unroll
            for (int j = 0; j < 8; ++j) {
                float v = gamma[kbase + j] * A[(size_t)(kbase + j) * NS + col];
                unsigned tb = f32bits(v);
                hb[j] = tb & 0xFFFF0000u;
                lb[j] = f32bits(v - bitsf32(hb[j]));
            }
            uint4 ph, pl;
            ph.x = (hb[0] >> 16) | hb[1]; ph.y = (hb[2] >> 16) | hb[3];
            ph.z = (hb[4] >> 16) | hb[5]; ph.w = (hb[6] >> 16) | hb[7];
            pl.x = (lb[0] >> 16) | (lb[1] & 0xFFFF0000u);
            pl.y = (lb[2] >> 16) | (lb[3] & 0xFFFF0000u);
            pl.z = (lb[4] >> 16) | (lb[5] & 0xFFFF0000u);
            pl.w = (lb[6] >> 16) | (lb[7] & 0xFFFF0000u);
            *reinterpret_cast<uint4*>(PAh + (size_t)g * 8) = ph;
            *reinterpret_cast<uint4*>(PAl + (size_t)g * 8) = pl;
        } else {
            const int g2   = g - 4096;         // 0..4095
            const int lane = g2 & 63;
            const int kt   = (g2 >> 6) & 1;
            const int offs = (g2 >> 7) & 1;
            const int dblk = g2 >> 8;          // 0..15
            const int i    = lane & 15;
            const int d    = dblk * 32 + ((i >> 2) * 8) + offs * 4 + (i & 3);
            const int nb   = kt * 32 + (lane >> 4) * 8;
            unsigned short v[8];
            #pragma unroll
            for (int j = 0; j < 8; ++j) v[j] = f2bf(C[(size_t)d * NS + nb + j]);
            uint4 p;
            p.x = v[0] | ((unsigned)v[1] << 16); p.y = v[2] | ((unsigned)v[3] << 16);
            p.z = v[4] | ((unsigned)v[5] << 16); p.w = v[6] | ((unsigned)v[7] << 16);
            *reinterpret_cast<uint4*>(PC2 + (size_t)g2 * 8) = p;
        }
    } else {
        // block 32: c0[n] = sum_k beta[k]*A[k][n]; gd, bd
        __shared__ float red[256];
        #pragma unroll
        for (int i = 0; i < 2; ++i) {
            int d = tid + 256 * i;
            gd[d] = gamma[d] * Dv[d];
            bd[d] = beta[d] * Dv[d];
        }
        const int n = tid & 63, part = tid >> 6;
        float s = 0.f;
        #pragma unroll 8
        for (int k = part * 128; k < part * 128 + 128; ++k)
            s += beta[k] * A[(size_t)k * NS + n];
        red[tid] = s;
        __syncthreads();
        if (tid < 64)
            c0[tid] = red[tid] + red[tid + 64] + red[tid + 128] + red[tid + 192];
    }
}

// ---- Kernel 1: Bu = z @ A' + c0 (R8's best-measured variant).
// 512 thr = 8 waves; 128 rows/block; grid 256. ALL of A' (128 KB) staged to
// LDS once (single barrier); lane's full row-stripe in 128 VGPRs (x read
// exactly once); stats from registers; MFMA phase touches no global. ----
__global__ __launch_bounds__(512, 2) void k_gemmA(const float* __restrict__ x,
                                               const unsigned short* __restrict__ PAh,
                                               const unsigned short* __restrict__ PAl,
                                               const float* __restrict__ c0,
                                               float* __restrict__ stats,
                                               float* __restrict__ Bu) {
    __shared__ unsigned short AsH[4 * 16 * 64 * 8];  // 64 KB
    __shared__ unsigned short AsL[4 * 16 * 64 * 8];  // 64 KB
    const int tid  = threadIdx.x;
    const int r0   = blockIdx.x * 128;
    const int w    = tid >> 6;
    const int lane = tid & 63;
    const int myrow = 16 * w + (lane & 15);
    const int kb    = (lane >> 4) * 8;
    const float* xrow = x + (size_t)(r0 + myrow) * DM;

    {
        const float4* sh = reinterpret_cast<const float4*>(PAh);
        const float4* sl = reinterpret_cast<const float4*>(PAl);
        float4* dh = reinterpret_cast<float4*>(AsH);
        float4* dl = reinterpret_cast<float4*>(AsL);
        #pragma unroll
        for (int i = 0; i < 8; ++i) {
            dh[tid + 512 * i] = sh[tid + 512 * i];
            dl[tid + 512 * i] = sl[tid + 512 * i];
        }
    }

    float4 xv[32];
    #pragma unroll
    for (int kc = 0; kc < 4; ++kc) {
        #pragma unroll
        for (int k32 = 0; k32 < 4; ++k32) {
            xv[kc * 8 + 2 * k32]     = *reinterpret_cast<const float4*>(
                xrow + kc * 128 + k32 * 32 + kb);
            xv[kc * 8 + 2 * k32 + 1] = *reinterpret_cast<const float4*>(
                xrow + kc * 128 + k32 * 32 + kb + 4);
        }
    }

    float s = 0.f, s2 = 0.f;
    #pragma unroll
    for (int i = 0; i < 32; ++i) {
        float4 a = xv[i];
        s  += (a.x + a.y) + (a.z + a.w);
        s2 += a.x*a.x + a.y*a.y + a.z*a.z + a.w*a.w;
    }
    s += __shfl_xor(s, 16); s2 += __shfl_xor(s2, 16);
    s += __shfl_xor(s, 32); s2 += __shfl_xor(s2, 32);
    const float mean = s * (1.0f / DM);
    const float var  = s2 * (1.0f / DM) - mean * mean;
    const float rstd = rsqrtf(var + LN_EPS);
    const float m2   = -mean * rstd;
    if (lane < 16) {
        stats[2 * (r0 + myrow)]     = mean;
        stats[2 * (r0 + myrow) + 1] = rstd;
    }

    __syncthreads();   // A' staged; the only barrier

    f32x4 acc[4] = {};
    const bf16x8* ABh = reinterpret_cast<const bf16x8*>(AsH);
    const bf16x8* ABl = reinterpret_cast<const bf16x8*>(AsL);
    #pragma unroll
    for (int kc = 0; kc < 4; ++kc) {
        #pragma unroll
        for (int k32 = 0; k32 < 4; ++k32) {
            bf16x8 ah, al;
            norm_split8(xv[kc * 8 + 2 * k32], xv[kc * 8 + 2 * k32 + 1], rstd, m2, ah, al);
            #pragma unroll
            for (int ct = 0; ct < 4; ++ct) {
                const int fi = ((kc * 4 + k32) * 4 + ct) * 64 + lane;
                bf16x8 bh = ABh[fi];
                bf16x8 bl = ABl[fi];
                acc[ct] = __builtin_amdgcn_mfma_f32_16x16x32_bf16(ah, bh, acc[ct], 0, 0, 0);
                acc[ct] = __builtin_amdgcn_mfma_f32_16x16x32_bf16(ah, bl, acc[ct], 0, 0, 0);
                acc[ct] = __builtin_amdgcn_mfma_f32_16x16x32_bf16(al, bh, acc[ct], 0, 0, 0);
            }
        }
    }

    const int orow = r0 + 16 * w + (lane >> 4) * 4;
    #pragma unroll
    for (int ct = 0; ct < 4; ++ct) {
        const int n = ct * 16 + (lane & 15);
        const float c0n = c0[n];
        #pragma unroll
        for (int j = 0; j < 4; ++j)
            Bu[(size_t)(orow + j) * NS + n] = acc[ct][j] + c0n;
    }
}

// ---- Kernel 2: fused scan + swapped-operand gemmC, SOFTWARE-PIPELINED with
// EARLY x PREFETCH: each thread issues its 16 phase-3 x float4 loads (and
// stats) at kernel entry, BEFORE the scan phase -> 64 MB of x latency hides
// under the ~4 us scan. Phase 3: 2 passes of 4 dblks, each pass preloads all
// 16 C-fragments before MFMA (R18-validated). Regular stores. ----
__global__ __launch_bounds__(512, 4) void k_scanC(const float* __restrict__ x,
                                                  const unsigned short* __restrict__ PC2,
                                                  const float* __restrict__ gd,
                                                  const float* __restrict__ bd,
                                                  const float* __restrict__ stats,
                                                  const float* __restrict__ Bu,
                                                  float* __restrict__ out) {
    __shared__ __align__(16) char smem[8192 + 4096];   // h (8K) + gd/bd (4K)
    const int tid = threadIdx.x;
    const int seg = blockIdx.x & (SEGS - 1);
    const int b   = blockIdx.x >> 5;
    const int l0  = seg * LSEG;
    const int rowbase = b * L_ + l0;         // first live row

    // ---- EARLY: issue phase-3 x loads + stats before anything else ----
    const int w    = tid >> 6;
    const int lane = tid & 63;
    const int rg   = w & 3;
    const int q    = w >> 2;                     // 0..1
    const int hr   = rg * 16 + (lane & 15);      // local row 0..63
    const int kb   = (lane >> 4) * 8;
    const size_t grow = (size_t)rowbase + hr;
    const float* xrp = x + grow * DM;
    float* orp = out + grow * DM;

    float4 xp0[8], xp1[8];
    #pragma unroll
    for (int pi = 0; pi < 8; ++pi) {
        const int dblk = q * 8 + pi;
        const int db = dblk * 32 + kb;
        xp0[pi] = *reinterpret_cast<const float4*>(xrp + db);
        xp1[pi] = *reinterpret_cast<const float4*>(xrp + db + 4);
    }
    const float mean = stats[2 * grow];
    const float rstd = stats[2 * grow + 1];

    // ---- scan phase (wave 0) / gd-bd staging (waves 1-7) ----
    if (tid < 64) {
        constexpr int G = 16;
        const int n     = tid;
        const int start = (seg == 0) ? 0 : (l0 - WARM);
        const int skip  = l0 - start;            // 0 or 64
        const int nGrp  = (l0 + LSEG - start) / G;
        const float* bp = Bu + ((size_t)b * L_ + start) * NS + n;
        char* hbase = smem;

        float bufA[G], bufB[G];
        #pragma unroll
        for (int j = 0; j < G; ++j) bufA[j] = KLN * bp[(size_t)j * NS];
        float hv = 0.0f;
        int g = 0;
        for (;;) {
            {
                if (g + 1 < nGrp) {
                    const int base = (g + 1) * G;
                    #pragma unroll
                    for (int j = 0; j < G; ++j)
                        bufB[j] = KLN * bp[(size_t)(base + j) * NS];
                }
                const int lbase = g * G - skip;
                const bool doStore = lbase >= 0;
                #pragma unroll
                for (int j = 0; j < G; ++j) {
                    float t = fmaf(hv, KLN, bufA[j]);
                    float e = __builtin_amdgcn_exp2f(t);
                    float rr = __builtin_amdgcn_rcpf(e + 1.0f);
                    hv = fmaf(-2.0f, rr, 1.0f);
                    if (doStore) {
                        const int lr = lbase + j;
                        *reinterpret_cast<unsigned short*>(
                            hbase + lr * 128 + ((2 * n) ^ ((lr & 7) << 4))) = f2bf(hv);
                    }
                }
            }
            if (++g == nGrp) break;
            {
                if (g + 1 < nGrp) {
                    const int base = (g + 1) * G;
                    #pragma unroll
                    for (int j = 0; j < G; ++j)
                        bufA[j] = KLN * bp[(size_t)(base + j) * NS];
                }
                const int lbase = g * G - skip;
                const bool doStore = lbase >= 0;
                #pragma unroll
                for (int j = 0; j < G; ++j) {
                    float t = fmaf(hv, KLN, bufB[j]);
                    float e = __builtin_amdgcn_exp2f(t);
                    float rr = __builtin_amdgcn_rcpf(e + 1.0f);
                    hv = fmaf(-2.0f, rr, 1.0f);
                    if (doStore) {
                        const int lr = lbase + j;
                        *reinterpret_cast<unsigned short*>(
                            hbase + lr * 128 + ((2 * n) ^ ((lr & 7) << 4))) = f2bf(hv);
                    }
                }
            }
            if (++g == nGrp) break;
        }
    } else {
        float* GdS = (float*)(smem + 8192);
        const int t2 = tid - 64;                 // 0..447
        if (t2 < 256)
            reinterpret_cast<float4*>(GdS)[t2] =
                (t2 < 128) ? reinterpret_cast<const float4*>(gd)[t2]
                           : reinterpret_cast<const float4*>(bd)[t2 - 128];
    }
    __syncthreads();

    // ---- phase 3: wave w -> row-group (w&3), d-quarter (w>>2) ----
    bf16x8 hfr0 = *reinterpret_cast<const bf16x8*>(
        smem + hr * 128 + (((lane >> 4) * 16) ^ ((hr & 7) << 4)));
    bf16x8 hfr1 = *reinterpret_cast<const bf16x8*>(
        smem + hr * 128 + ((64 + (lane >> 4) * 16) ^ ((hr & 7) << 4)));

    const float* GdS = (const float*)(smem + 8192);
    const float* BdS = GdS + DM;

    #pragma unroll
    for (int pass = 0; pass < 2; ++pass) {
        // -------- preload C fragments for 4 dblks (all independent) --------
        bf16x8 cf0[4], cf1[4], cf2[4], cf3[4];
        #pragma unroll
        for (int i = 0; i < 4; ++i) {
            const int dblk = q * 8 + pass * 4 + i;
            cf0[i] = *reinterpret_cast<const bf16x8*>(PC2 + ((size_t)dblk * 256 + lane) * 8);
            cf1[i] = *reinterpret_cast<const bf16x8*>(PC2 + ((size_t)dblk * 256 + 64 + lane) * 8);
            cf2[i] = *reinterpret_cast<const bf16x8*>(PC2 + ((size_t)dblk * 256 + 128 + lane) * 8);
            cf3[i] = *reinterpret_cast<const bf16x8*>(PC2 + ((size_t)dblk * 256 + 192 + lane) * 8);
        }
        // -------- compute + epilogue + store --------
        #pragma unroll
        for (int i = 0; i < 4; ++i) {
            const int dblk = q * 8 + pass * 4 + i;
            f32x4 a0 = {}, a1 = {};
            a0 = __builtin_amdgcn_mfma_f32_16x16x32_bf16(cf0[i], hfr0, a0, 0, 0, 0);
            a0 = __builtin_amdgcn_mfma_f32_16x16x32_bf16(cf1[i], hfr1, a0, 0, 0, 0);
            a1 = __builtin_amdgcn_mfma_f32_16x16x32_bf16(cf2[i], hfr0, a1, 0, 0, 0);
            a1 = __builtin_amdgcn_mfma_f32_16x16x32_bf16(cf3[i], hfr1, a1, 0, 0, 0);

            const int db = dblk * 32 + kb;
            const float4 x0 = xp0[pass * 4 + i];
            const float4 x1 = xp1[pass * 4 + i];
            const float4 g0 = *reinterpret_cast<const float4*>(GdS + db);
            const float4 g1 = *reinterpret_cast<const float4*>(GdS + db + 4);
            const float4 d0 = *reinterpret_cast<const float4*>(BdS + db);
            const float4 d1 = *reinterpret_cast<const float4*>(BdS + db + 4);
            float4 o0, o1;
            o0.x = fmaf((x0.x - mean) * rstd, g0.x, a0[0] + d0.x + x0.x);
            o0.y = fmaf((x0.y - mean) * rstd, g0.y, a0[1] + d0.y + x0.y);
            o0.z = fmaf((x0.z - mean) * rstd, g0.z, a0[2] + d0.z + x0.z);
            o0.w = fmaf((x0.w - mean) * rstd, g0.w, a0[3] + d0.w + x0.w);
            o1.x = fmaf((x1.x - mean) * rstd, g1.x, a1[0] + d1.x + x1.x);
            o1.y = fmaf((x1.y - mean) * rstd, g1.y, a1[1] + d1.y + x1.y);
            o1.z = fmaf((x1.z - mean) * rstd, g1.z, a1[2] + d1.z + x1.z);
            o1.w = fmaf((x1.w - mean) * rstd, g1.w, a1[3] + d1.w + x1.w);
            *reinterpret_cast<float4*>(orp + db)     = o0;
            *reinterpret_cast<float4*>(orp + db + 4) = o1;
        }
    }
}

extern "C" void kernel_launch(void* const* d_in, const int* in_sizes, int n_in,
                              void* d_out, int out_size, void* d_ws, size_t ws_size,
                              hipStream_t stream) {
    const float* x     = (const float*)d_in[0];
    const float* A     = (const float*)d_in[1];
    const float* C     = (const float*)d_in[2];
    const float* Dv    = (const float*)d_in[3];
    const float* gamma = (const float*)d_in[4];
    const float* beta  = (const float*)d_in[5];
    float* out = (float*)d_out;

    char* p = (char*)d_ws;
    float* Bu           = (float*)p;                 p += (size_t)BL * NS * 4;   // 8 MB
    float* stats        = (float*)p;                 p += (size_t)BL * 2 * 4;    // 256 KB
    unsigned short* PAh = (unsigned short*)p;        p += (size_t)DM * NS * 2;
    unsigned short* PAl = (unsigned short*)p;        p += (size_t)DM * NS * 2;
    unsigned short* PC2 = (unsigned short*)p;        p += (size_t)DM * NS * 2;
    float* c0           = (float*)p;                 p += 256;
    float* gd           = (float*)p;                 p += (size_t)DM * 4;
    float* bd           = (float*)p;

    k_pack<<<33, 256, 0, stream>>>(A, C, gamma, beta, Dv, PAh, PAl, PC2, c0, gd, bd);
    k_gemmA<<<BL / 128, 512, 0, stream>>>(x, PAh, PAl, c0, stats, Bu);
    k_scanC<<<B_ * SEGS, 512, 0, stream>>>(x, PC2, gd, bd, stats, Bu, out);
}

// Round 20
// 62.909 us; speedup vs baseline: 1.0323x; 1.0323x over previous
//
#include <hip/hip_runtime.h>
#include <hip/hip_bf16.h>

typedef short bf16x8 __attribute__((ext_vector_type(8)));
typedef float f32x4 __attribute__((ext_vector_type(4)));

constexpr int B_ = 16;
constexpr int L_ = 2048;
constexpr int DM = 512;
constexpr int NS = 64;
constexpr int BL = B_ * L_;          // 32768 rows
constexpr float LN_EPS = 1e-5f;
constexpr float KLN = 2.8853900817779268f;   // 2*log2(e)

constexpr int SEGS = 32;
constexpr int LSEG = L_ / SEGS;      // 64 live rows per scan
constexpr int WARM = 64;

__device__ __forceinline__ unsigned f32bits(float f) {
    union { float f; unsigned u; } v{f}; return v.u;
}
__device__ __forceinline__ float bitsf32(unsigned u) {
    union { unsigned u; float f; } v{u}; return v.f;
}
__device__ __forceinline__ unsigned short f2bf(float f) {   // RNE
    unsigned u = f32bits(f);
    unsigned r = u + 0x7FFF + ((u >> 16) & 1);
    return (unsigned short)(r >> 16);
}

// normalize 8 consecutive-k x values and split into hi/lo bf16 fragments.
__device__ __forceinline__ void norm_split8(float4 u0, float4 u1,
                                            float rstd, float m2,
                                            bf16x8& ah, bf16x8& al) {
    float t[8] = { fmaf(u0.x, rstd, m2), fmaf(u0.y, rstd, m2),
                   fmaf(u0.z, rstd, m2), fmaf(u0.w, rstd, m2),
                   fmaf(u1.x, rstd, m2), fmaf(u1.y, rstd, m2),
                   fmaf(u1.z, rstd, m2), fmaf(u1.w, rstd, m2) };
    unsigned hb[8], lb[8];
    #pragma unroll
    for (int j = 0; j < 8; ++j) {
        unsigned tb = f32bits(t[j]);
        hb[j] = tb & 0xFFFF0000u;
        lb[j] = f32bits(t[j] - bitsf32(hb[j]));
    }
    union { unsigned u[4]; bf16x8 v; } H, L;
    #pragma unroll
    for (int p = 0; p < 4; ++p) {
        H.u[p] = (hb[2*p] >> 16) | hb[2*p+1];
        L.u[p] = (lb[2*p] >> 16) | (lb[2*p+1] & 0xFFFF0000u);
    }
    ah = H.v; al = L.v;
}

// ---- Kernel 0: pack A' = diag(gamma)@A split MFMA-B fragments; C into the
//      swapped-operand interleaved fragment order PC2 (validated R9/R12);
//      c0 = beta@A; gd = gamma*D; bd = beta*D ----
__global__ __launch_bounds__(256) void k_pack(const float* __restrict__ A,
                                              const float* __restrict__ C,
                                              const float* __restrict__ gamma,
                                              const float* __restrict__ beta,
                                              const float* __restrict__ Dv,
                                              unsigned short* __restrict__ PAh,
                                              unsigned short* __restrict__ PAl,
                                              unsigned short* __restrict__ PC2,
                                              float* __restrict__ c0,
                                              float* __restrict__ gd,
                                              float* __restrict__ bd) {
    const int blk = blockIdx.x;
    const int tid = threadIdx.x;
    if (blk < 32) {
        const int g = blk * 256 + tid;     // 0..8191
        if (g < 4096) {
            const int lane = g & 63, ct = (g >> 6) & 3, k32 = (g >> 8) & 3, kc = g >> 10;
            const int kbase = kc * 128 + k32 * 32 + (lane >> 4) * 8;
            const int col   = ct * 16 + (lane & 15);
            unsigned hb[8], lb[8];
            #pragma unroll
            for (int j = 0; j < 8; ++j) {
                float v = gamma[kbase + j] * A[(size_t)(kbase + j) * NS + col];
                unsigned tb = f32bits(v);
                hb[j] = tb & 0xFFFF0000u;
                lb[j] = f32bits(v - bitsf32(hb[j]));
            }
            uint4 ph, pl;
            ph.x = (hb[0] >> 16) | hb[1]; ph.y = (hb[2] >> 16) | hb[3];
            ph.z = (hb[4] >> 16) | hb[5]; ph.w = (hb[6] >> 16) | hb[7];
            pl.x = (lb[0] >> 16) | (lb[1] & 0xFFFF0000u);
            pl.y = (lb[2] >> 16) | (lb[3] & 0xFFFF0000u);
            pl.z = (lb[4] >> 16) | (lb[5] & 0xFFFF0000u);
            pl.w = (lb[6] >> 16) | (lb[7] & 0xFFFF0000u);
            *reinterpret_cast<uint4*>(PAh + (size_t)g * 8) = ph;
            *reinterpret_cast<uint4*>(PAl + (size_t)g * 8) = pl;
        } else {
            const int g2   = g - 4096;         // 0..4095
            const int lane = g2 & 63;
            const int kt   = (g2 >> 6) & 1;
            const int offs = (g2 >> 7) & 1;
            const int dblk = g2 >> 8;          // 0..15
            const int i    = lane & 15;
            const int d    = dblk * 32 + ((i >> 2) * 8) + offs * 4 + (i & 3);
            const int nb   = kt * 32 + (lane >> 4) * 8;
            unsigned short v[8];
            #pragma unroll
            for (int j = 0; j < 8; ++j) v[j] = f2bf(C[(size_t)d * NS + nb + j]);
            uint4 p;
            p.x = v[0] | ((unsigned)v[1] << 16); p.y = v[2] | ((unsigned)v[3] << 16);
            p.z = v[4] | ((unsigned)v[5] << 16); p.w = v[6] | ((unsigned)v[7] << 16);
            *reinterpret_cast<uint4*>(PC2 + (size_t)g2 * 8) = p;
        }
    } else {
        // block 32: c0[n] = sum_k beta[k]*A[k][n]; gd, bd
        __shared__ float red[256];
        #pragma unroll
        for (int i = 0; i < 2; ++i) {
            int d = tid + 256 * i;
            gd[d] = gamma[d] * Dv[d];
            bd[d] = beta[d] * Dv[d];
        }
        const int n = tid & 63, part = tid >> 6;
        float s = 0.f;
        #pragma unroll 8
        for (int k = part * 128; k < part * 128 + 128; ++k)
            s += beta[k] * A[(size_t)k * NS + n];
        red[tid] = s;
        __syncthreads();
        if (tid < 64)
            c0[tid] = red[tid] + red[tid + 64] + red[tid + 128] + red[tid + 192];
    }
}

// ---- Kernel 1: Bu = z @ A' + c0 (R8's best-measured variant).
// 512 thr = 8 waves; 128 rows/block; grid 256. ALL of A' (128 KB) staged to
// LDS once (single barrier); lane's full row-stripe in 128 VGPRs (x read
// exactly once); stats from registers; MFMA phase touches no global. ----
__global__ __launch_bounds__(512, 2) void k_gemmA(const float* __restrict__ x,
                                               const unsigned short* __restrict__ PAh,
                                               const unsigned short* __restrict__ PAl,
                                               const float* __restrict__ c0,
                                               float* __restrict__ stats,
                                               float* __restrict__ Bu) {
    __shared__ unsigned short AsH[4 * 16 * 64 * 8];  // 64 KB
    __shared__ unsigned short AsL[4 * 16 * 64 * 8];  // 64 KB
    const int tid  = threadIdx.x;
    const int r0   = blockIdx.x * 128;
    const int w    = tid >> 6;
    const int lane = tid & 63;
    const int myrow = 16 * w + (lane & 15);
    const int kb    = (lane >> 4) * 8;
    const float* xrow = x + (size_t)(r0 + myrow) * DM;

    {
        const float4* sh = reinterpret_cast<const float4*>(PAh);
        const float4* sl = reinterpret_cast<const float4*>(PAl);
        float4* dh = reinterpret_cast<float4*>(AsH);
        float4* dl = reinterpret_cast<float4*>(AsL);
        #pragma unroll
        for (int i = 0; i < 8; ++i) {
            dh[tid + 512 * i] = sh[tid + 512 * i];
            dl[tid + 512 * i] = sl[tid + 512 * i];
        }
    }

    float4 xv[32];
    #pragma unroll
    for (int kc = 0; kc < 4; ++kc) {
        #pragma unroll
        for (int k32 = 0; k32 < 4; ++k32) {
            xv[kc * 8 + 2 * k32]     = *reinterpret_cast<const float4*>(
                xrow + kc * 128 + k32 * 32 + kb);
            xv[kc * 8 + 2 * k32 + 1] = *reinterpret_cast<const float4*>(
                xrow + kc * 128 + k32 * 32 + kb + 4);
        }
    }

    float s = 0.f, s2 = 0.f;
    #pragma unroll
    for (int i = 0; i < 32; ++i) {
        float4 a = xv[i];
        s  += (a.x + a.y) + (a.z + a.w);
        s2 += a.x*a.x + a.y*a.y + a.z*a.z + a.w*a.w;
    }
    s += __shfl_xor(s, 16); s2 += __shfl_xor(s2, 16);
    s += __shfl_xor(s, 32); s2 += __shfl_xor(s2, 32);
    const float mean = s * (1.0f / DM);
    const float var  = s2 * (1.0f / DM) - mean * mean;
    const float rstd = rsqrtf(var + LN_EPS);
    const float m2   = -mean * rstd;
    if (lane < 16) {
        stats[2 * (r0 + myrow)]     = mean;
        stats[2 * (r0 + myrow) + 1] = rstd;
    }

    __syncthreads();   // A' staged; the only barrier

    f32x4 acc[4] = {};
    const bf16x8* ABh = reinterpret_cast<const bf16x8*>(AsH);
    const bf16x8* ABl = reinterpret_cast<const bf16x8*>(AsL);
    #pragma unroll
    for (int kc = 0; kc < 4; ++kc) {
        #pragma unroll
        for (int k32 = 0; k32 < 4; ++k32) {
            bf16x8 ah, al;
            norm_split8(xv[kc * 8 + 2 * k32], xv[kc * 8 + 2 * k32 + 1], rstd, m2, ah, al);
            #pragma unroll
            for (int ct = 0; ct < 4; ++ct) {
                const int fi = ((kc * 4 + k32) * 4 + ct) * 64 + lane;
                bf16x8 bh = ABh[fi];
                bf16x8 bl = ABl[fi];
                acc[ct] = __builtin_amdgcn_mfma_f32_16x16x32_bf16(ah, bh, acc[ct], 0, 0, 0);
                acc[ct] = __builtin_amdgcn_mfma_f32_16x16x32_bf16(ah, bl, acc[ct], 0, 0, 0);
                acc[ct] = __builtin_amdgcn_mfma_f32_16x16x32_bf16(al, bh, acc[ct], 0, 0, 0);
            }
        }
    }

    const int orow = r0 + 16 * w + (lane >> 4) * 4;
    #pragma unroll
    for (int ct = 0; ct < 4; ++ct) {
        const int n = ct * 16 + (lane & 15);
        const float c0n = c0[n];
        #pragma unroll
        for (int j = 0; j < 4; ++j)
            Bu[(size_t)(orow + j) * NS + n] = acc[ct][j] + c0n;
    }
}

// ---- Kernel 2: fused scan + swapped-operand gemmC, SOFTWARE-PIPELINED.
// Grid 512 = 16 b x 32 seg (LSEG 64, low warmup redundancy). Wave 0 scans
// 128 steps -> h in XOR-swizzled LDS; waves 1-7 stage gd/bd. Phase 3: each
// wave covers (row-group w&3) x (d-quarter w>>2), in 2 passes of 4 dblks;
// each pass PRELOADS all 16 C-fragments + 8 x-float4 before any MFMA ->
// 2 latency exposures instead of 8. Regular stores. (R18: best measured.) ----
__global__ __launch_bounds__(512, 4) void k_scanC(const float* __restrict__ x,
                                                  const unsigned short* __restrict__ PC2,
                                                  const float* __restrict__ gd,
                                                  const float* __restrict__ bd,
                                                  const float* __restrict__ stats,
                                                  const float* __restrict__ Bu,
                                                  float* __restrict__ out) {
    __shared__ __align__(16) char smem[8192 + 4096];   // h (8K) + gd/bd (4K)
    const int tid = threadIdx.x;
    const int seg = blockIdx.x & (SEGS - 1);
    const int b   = blockIdx.x >> 5;
    const int l0  = seg * LSEG;
    const int rowbase = b * L_ + l0;         // first live row

    if (tid < 64) {
        constexpr int G = 16;
        const int n     = tid;
        const int start = (seg == 0) ? 0 : (l0 - WARM);
        const int skip  = l0 - start;            // 0 or 64
        const int nGrp  = (l0 + LSEG - start) / G;
        const float* bp = Bu + ((size_t)b * L_ + start) * NS + n;
        char* hbase = smem;

        float bufA[G], bufB[G];
        #pragma unroll
        for (int j = 0; j < G; ++j) bufA[j] = KLN * bp[(size_t)j * NS];
        float hv = 0.0f;
        int g = 0;
        for (;;) {
            {
                if (g + 1 < nGrp) {
                    const int base = (g + 1) * G;
                    #pragma unroll
                    for (int j = 0; j < G; ++j)
                        bufB[j] = KLN * bp[(size_t)(base + j) * NS];
                }
                const int lbase = g * G - skip;
                const bool doStore = lbase >= 0;
                #pragma unroll
                for (int j = 0; j < G; ++j) {
                    float t = fmaf(hv, KLN, bufA[j]);
                    float e = __builtin_amdgcn_exp2f(t);
                    float rr = __builtin_amdgcn_rcpf(e + 1.0f);
                    hv = fmaf(-2.0f, rr, 1.0f);
                    if (doStore) {
                        const int lr = lbase + j;
                        *reinterpret_cast<unsigned short*>(
                            hbase + lr * 128 + ((2 * n) ^ ((lr & 7) << 4))) = f2bf(hv);
                    }
                }
            }
            if (++g == nGrp) break;
            {
                if (g + 1 < nGrp) {
                    const int base = (g + 1) * G;
                    #pragma unroll
                    for (int j = 0; j < G; ++j)
                        bufA[j] = KLN * bp[(size_t)(base + j) * NS];
                }
                const int lbase = g * G - skip;
                const bool doStore = lbase >= 0;
                #pragma unroll
                for (int j = 0; j < G; ++j) {
                    float t = fmaf(hv, KLN, bufB[j]);
                    float e = __builtin_amdgcn_exp2f(t);
                    float rr = __builtin_amdgcn_rcpf(e + 1.0f);
                    hv = fmaf(-2.0f, rr, 1.0f);
                    if (doStore) {
                        const int lr = lbase + j;
                        *reinterpret_cast<unsigned short*>(
                            hbase + lr * 128 + ((2 * n) ^ ((lr & 7) << 4))) = f2bf(hv);
                    }
                }
            }
            if (++g == nGrp) break;
        }
    } else {
        float* GdS = (float*)(smem + 8192);
        const int t2 = tid - 64;                 // 0..447
        if (t2 < 256)
            reinterpret_cast<float4*>(GdS)[t2] =
                (t2 < 128) ? reinterpret_cast<const float4*>(gd)[t2]
                           : reinterpret_cast<const float4*>(bd)[t2 - 128];
    }
    __syncthreads();

    // ---- phase 3: wave w -> row-group (w&3), d-quarter (w>>2) ----
    const int w    = tid >> 6;
    const int lane = tid & 63;
    const int rg   = w & 3;
    const int q    = w >> 2;                     // 0..1
    const int hr   = rg * 16 + (lane & 15);      // local row 0..63
    const int kb   = (lane >> 4) * 8;
    const size_t grow = (size_t)rowbase + hr;
    const float mean = stats[2 * grow];
    const float rstd = stats[2 * grow + 1];

    bf16x8 hfr0 = *reinterpret_cast<const bf16x8*>(
        smem + hr * 128 + (((lane >> 4) * 16) ^ ((hr & 7) << 4)));
    bf16x8 hfr1 = *reinterpret_cast<const bf16x8*>(
        smem + hr * 128 + ((64 + (lane >> 4) * 16) ^ ((hr & 7) << 4)));

    const float* GdS = (const float*)(smem + 8192);
    const float* BdS = GdS + DM;
    const float* xrp = x + grow * DM;
    float* orp = out + grow * DM;

    #pragma unroll
    for (int pass = 0; pass < 2; ++pass) {
        // -------- preload everything for 4 dblks (all independent) --------
        bf16x8 cf0[4], cf1[4], cf2[4], cf3[4];
        float4 xp0[4], xp1[4];
        #pragma unroll
        for (int i = 0; i < 4; ++i) {
            const int dblk = q * 8 + pass * 4 + i;
            cf0[i] = *reinterpret_cast<const bf16x8*>(PC2 + ((size_t)dblk * 256 + lane) * 8);
            cf1[i] = *reinterpret_cast<const bf16x8*>(PC2 + ((size_t)dblk * 256 + 64 + lane) * 8);
            cf2[i] = *reinterpret_cast<const bf16x8*>(PC2 + ((size_t)dblk * 256 + 128 + lane) * 8);
            cf3[i] = *reinterpret_cast<const bf16x8*>(PC2 + ((size_t)dblk * 256 + 192 + lane) * 8);
            const int db = dblk * 32 + kb;
            xp0[i] = *reinterpret_cast<const float4*>(xrp + db);
            xp1[i] = *reinterpret_cast<const float4*>(xrp + db + 4);
        }
        // -------- compute + epilogue + store --------
        #pragma unroll
        for (int i = 0; i < 4; ++i) {
            const int dblk = q * 8 + pass * 4 + i;
            f32x4 a0 = {}, a1 = {};
            a0 = __builtin_amdgcn_mfma_f32_16x16x32_bf16(cf0[i], hfr0, a0, 0, 0, 0);
            a0 = __builtin_amdgcn_mfma_f32_16x16x32_bf16(cf1[i], hfr1, a0, 0, 0, 0);
            a1 = __builtin_amdgcn_mfma_f32_16x16x32_bf16(cf2[i], hfr0, a1, 0, 0, 0);
            a1 = __builtin_amdgcn_mfma_f32_16x16x32_bf16(cf3[i], hfr1, a1, 0, 0, 0);

            const int db = dblk * 32 + kb;
            const float4 x0 = xp0[i];
            const float4 x1 = xp1[i];
            const float4 g0 = *reinterpret_cast<const float4*>(GdS + db);
            const float4 g1 = *reinterpret_cast<const float4*>(GdS + db + 4);
            const float4 d0 = *reinterpret_cast<const float4*>(BdS + db);
            const float4 d1 = *reinterpret_cast<const float4*>(BdS + db + 4);
            float4 o0, o1;
            o0.x = fmaf((x0.x - mean) * rstd, g0.x, a0[0] + d0.x + x0.x);
            o0.y = fmaf((x0.y - mean) * rstd, g0.y, a0[1] + d0.y + x0.y);
            o0.z = fmaf((x0.z - mean) * rstd, g0.z, a0[2] + d0.z + x0.z);
            o0.w = fmaf((x0.w - mean) * rstd, g0.w, a0[3] + d0.w + x0.w);
            o1.x = fmaf((x1.x - mean) * rstd, g1.x, a1[0] + d1.x + x1.x);
            o1.y = fmaf((x1.y - mean) * rstd, g1.y, a1[1] + d1.y + x1.y);
            o1.z = fmaf((x1.z - mean) * rstd, g1.z, a1[2] + d1.z + x1.z);
            o1.w = fmaf((x1.w - mean) * rstd, g1.w, a1[3] + d1.w + x1.w);
            *reinterpret_cast<float4*>(orp + db)     = o0;
            *reinterpret_cast<float4*>(orp + db + 4) = o1;
        }
    }
}

extern "C" void kernel_launch(void* const* d_in, const int* in_sizes, int n_in,
                              void* d_out, int out_size, void* d_ws, size_t ws_size,
                              hipStream_t stream) {
    const float* x     = (const float*)d_in[0];
    const float* A     = (const float*)d_in[1];
    const float* C     = (const float*)d_in[2];
    const float* Dv    = (const float*)d_in[3];
    const float* gamma = (const float*)d_in[4];
    const float* beta  = (const float*)d_in[5];
    float* out = (float*)d_out;

    char* p = (char*)d_ws;
    float* Bu           = (float*)p;                 p += (size_t)BL * NS * 4;   // 8 MB
    float* stats        = (float*)p;                 p += (size_t)BL * 2 * 4;    // 256 KB
    unsigned short* PAh = (unsigned short*)p;        p += (size_t)DM * NS * 2;
    unsigned short* PAl = (unsigned short*)p;        p += (size_t)DM * NS * 2;
    unsigned short* PC2 = (unsigned short*)p;        p += (size_t)DM * NS * 2;
    float* c0           = (float*)p;                 p += 256;
    float* gd           = (float*)p;                 p += (size_t)DM * 4;
    float* bd           = (float*)p;

    k_pack<<<33, 256, 0, stream>>>(A, C, gamma, beta, Dv, PAh, PAl, PC2, c0, gd, bd);
    k_gemmA<<<BL / 128, 512, 0, stream>>>(x, PAh, PAl, c0, stats, Bu);
    k_scanC<<<B_ * SEGS, 512, 0, stream>>>(x, PC2, gd, bd, stats, Bu, out);
}